// Round 5
// baseline (600.584 us; speedup 1.0000x reference)
//
#include <hip/hip_runtime.h>

typedef _Float16 half8  __attribute__((ext_vector_type(8)));
typedef _Float16 half4v __attribute__((ext_vector_type(4)));
typedef float    f32x4  __attribute__((ext_vector_type(4)));

#define GAT_SLOPE 0.2f
#define N_SRC0 500000
#define N_DST0 65536
#define N_DST1 8192
#define E0 1048576
#define E1 131072
#define H 4

__device__ __forceinline__ float leaky(float x) { return x >= 0.f ? x : GAT_SLOPE * x; }

// One kernel for all setup work, flat-index region dispatch:
// R0 [0,65536):        BTs[n*1024+h*256+k] = (n<47) ? 0.25*Ws1[k*188+h*47+n] : 0
// R1 [+32768):         BT0[n*128+k] = fp16(Ws0[k*256+n])
// R2 [+2048):          WLR0[n*128+k] = n<4: dot64(Ws0 row, al0) ; n<8: dot64(Wd0,ar0); else 0
// R3 [+1024):          wl1[k*4+h] = dot47(Ws1, al1)
// R4 [+1024):          wr1[k*4+h] = dot47(Wd1, ar1)
// R5 [+E0+1):          seg0 starts
// R6 [+E1+1):          seg1 starts
__global__ __launch_bounds__(256) void prep_kernel(
    const float* __restrict__ Ws0, const float* __restrict__ Wd0,
    const float* __restrict__ al0, const float* __restrict__ ar0,
    const float* __restrict__ Ws1, const float* __restrict__ Wd1,
    const float* __restrict__ al1, const float* __restrict__ ar1,
    const int* __restrict__ dst0, const int* __restrict__ dst1,
    _Float16* __restrict__ BTs, _Float16* __restrict__ BT0,
    _Float16* __restrict__ WLR0, float* __restrict__ wl1, float* __restrict__ wr1,
    int* __restrict__ seg0, int* __restrict__ seg1) {
  int i = blockIdx.x * 256 + threadIdx.x;
  if (i < 65536) {
    int n = i >> 10, kk = i & 1023, h = kk >> 8, k = kk & 255;
    BTs[i] = (n < 47) ? (_Float16)(0.25f * Ws1[(size_t)k * 188 + h * 47 + n]) : (_Float16)0.f;
    return;
  }
  i -= 65536;
  if (i < 32768) {
    int nrow = i >> 7, k = i & 127;
    BT0[i] = (_Float16)Ws0[(size_t)k * 256 + nrow];
    return;
  }
  i -= 32768;
  if (i < 2048) {
    int n = i >> 7, k = i & 127;
    float v = 0.f;
    if (n < 4) {
      for (int d = 0; d < 64; ++d) v += Ws0[(size_t)k * 256 + n * 64 + d] * al0[n * 64 + d];
    } else if (n < 8) {
      int h = n - 4;
      for (int d = 0; d < 64; ++d) v += Wd0[(size_t)k * 256 + h * 64 + d] * ar0[h * 64 + d];
    }
    WLR0[i] = (_Float16)v;
    return;
  }
  i -= 2048;
  if (i < 1024) {
    int k = i >> 2, h = i & 3;
    float v = 0.f;
    for (int d = 0; d < 47; ++d) v += Ws1[(size_t)k * 188 + h * 47 + d] * al1[h * 47 + d];
    wl1[i] = v;
    return;
  }
  i -= 1024;
  if (i < 1024) {
    int k = i >> 2, h = i & 3;
    float v = 0.f;
    for (int d = 0; d < 47; ++d) v += Wd1[(size_t)k * 188 + h * 47 + d] * ar1[h * 47 + d];
    wr1[i] = v;
    return;
  }
  i -= 1024;
  if (i <= E0) {
    int lo = (i == 0) ? 0 : dst0[i - 1] + 1;
    int hi = (i == E0) ? N_DST0 : dst0[i];
    for (int d = lo; d <= hi; ++d) seg0[d] = i;
    return;
  }
  i -= (E0 + 1);
  if (i <= E1) {
    int lo = (i == 0) ? 0 : dst1[i - 1] + 1;
    int hi = (i == E1) ? N_DST1 : dst1[i];
    for (int d = lo; d <= hi; ++d) seg1[d] = i;
  }
}
#define PREP_TOTAL (65536 + 32768 + 2048 + 1024 + 1024 + (E0 + 1) + (E1 + 1))

// streaming: x fp32 -> xh fp16 (global), + MFMA el0/er0 = x @ WLR0(128x16)
__global__ __launch_bounds__(256) void cvt_elr_mfma_kernel(
    const float* __restrict__ x, const _Float16* __restrict__ WLR,
    _Float16* __restrict__ xh, float* __restrict__ el, float* __restrict__ er,
    int M, int n_dst) {
  __shared__ _Float16 As[128 * 128];
  const int t = threadIdx.x, lane = t & 63, wid = t >> 6;
  const int m0 = blockIdx.x * 128;
  for (int i = 0; i < 8; ++i) {
    int c = t + 256 * i;
    int row = c >> 4, j = c & 15;
    int gr = m0 + row;
    half8 va = {};
    if (gr < M) {
      float4 f0 = *(const float4*)(x + (size_t)gr * 128 + j * 8);
      float4 f1 = *(const float4*)(x + (size_t)gr * 128 + j * 8 + 4);
      va[0] = (_Float16)f0.x; va[1] = (_Float16)f0.y;
      va[2] = (_Float16)f0.z; va[3] = (_Float16)f0.w;
      va[4] = (_Float16)f1.x; va[5] = (_Float16)f1.y;
      va[6] = (_Float16)f1.z; va[7] = (_Float16)f1.w;
      *(half8*)(xh + (size_t)gr * 128 + j * 8) = va;
    }
    *(half8*)(&As[row * 128 + ((j ^ (row & 7)) << 3)]) = va;
  }
  half8 bf[4];
  for (int kc = 0; kc < 4; ++kc)
    bf[kc] = *(const half8*)(WLR + (lane & 15) * 128 + kc * 32 + (lane >> 4) * 8);
  __syncthreads();
  f32x4 acc[2] = {};
  for (int rt = 0; rt < 2; ++rt) {
    int row = (wid * 2 + rt) * 16 + (lane & 15);
    for (int kc = 0; kc < 4; ++kc) {
      int chunk = kc * 4 + (lane >> 4);
      half8 af = *(const half8*)(&As[row * 128 + ((chunk ^ (row & 7)) << 3)]);
      acc[rt] = __builtin_amdgcn_mfma_f32_16x16x32_f16(af, bf[kc], acc[rt], 0, 0, 0);
    }
  }
  int col = lane & 15, quad = lane >> 4;
  for (int rt = 0; rt < 2; ++rt)
    for (int r = 0; r < 4; ++r) {
      int row = m0 + (wid * 2 + rt) * 16 + quad * 4 + r;
      if (row < M) {
        if (col < 4) el[(size_t)row * 4 + col] = acc[rt][r];
        else if (col < 8 && row < n_dst) er[(size_t)row * 4 + col - 4] = acc[rt][r];
      }
    }
}

// FUSED layer-0 aggregation + feature GEMM + el1/er1 epilogue.
// 64 nodes/block (m0 = blockIdx*64), *** 512 thr = 8 waves *** (R4 bug: was 256).
// Agg: 16-lane group per node (8 waves x 4 groups x 2 rounds = 64 nodes);
//      each lane owns 8 channels exclusively -> no cross-lane reduce; alpha in
//      group regs (pass A), broadcast via shfl; result -> swizzled LDS As (fp16).
// GEMM: wave (h = wid>>1, wi = wid&1): head h, rows wi*32..wi*32+32;
//       B frags read directly from global BT0 (64 KB, L2-hot).
// el1/er1: shuffle-reduce over 16 col-lanes, LDS atomicAdd across heads, one
//          coalesced write per block.
__global__ __launch_bounds__(512) void agg_gemm0_kernel(
    const int* __restrict__ src, const int* __restrict__ seg,
    const float* __restrict__ el, const float* __restrict__ er,
    const _Float16* __restrict__ xh, const _Float16* __restrict__ BT,
    const float* __restrict__ b, const float* __restrict__ wl1,
    const float* __restrict__ wr1, _Float16* __restrict__ h0,
    float* __restrict__ el1, float* __restrict__ er1) {
  __shared__ _Float16 As[4 * 64 * 128];  // 64 KB: [h][node][128ch], XOR-swizzled
  __shared__ float elds[64][8];          // 2 KB: per-row el1[4], er1[4] partials
  const int t = threadIdx.x, lane = t & 63, wid = t >> 6;  // wid 0..7
  const int m0 = blockIdx.x * 64;
  const int g = lane >> 4, ci = lane & 15;
  if (t < 128) ((float4*)elds)[t] = float4{0.f, 0.f, 0.f, 0.f};

  for (int rnd = 0; rnd < 2; ++rnd) {
    const int j = rnd * 32 + wid * 4 + g;  // local node 0..63
    const int n = m0 + j;
    int s0 = seg[n], len = seg[n + 1] - s0;
    float4 erv = *(const float4*)(er + (size_t)n * 4);
    // pass A: alpha for edges ci+16*jj into regs; sums
    float a0[4], a1[4], a2[4], a3[4];
    int sr[4];
    float t0 = 0.f, t1 = 0.f, t2 = 0.f, t3 = 0.f;
#pragma unroll
    for (int jj = 0; jj < 4; ++jj) {
      int idx = ci + jj * 16;
      float v0 = 0.f, v1 = 0.f, v2 = 0.f, v3 = 0.f;
      int sv = 0;
      if (idx < len) {
        sv = src[s0 + idx];
        float4 e4 = *(const float4*)(el + (size_t)sv * 4);
        v0 = __expf(leaky(e4.x + erv.x)); v1 = __expf(leaky(e4.y + erv.y));
        v2 = __expf(leaky(e4.z + erv.z)); v3 = __expf(leaky(e4.w + erv.w));
        t0 += v0; t1 += v1; t2 += v2; t3 += v3;
      }
      a0[jj] = v0; a1[jj] = v1; a2[jj] = v2; a3[jj] = v3; sr[jj] = sv;
    }
    for (int idx = ci + 64; idx < len; idx += 16) {  // Poisson(16) tail: ~never
      int sv = src[s0 + idx];
      float4 e4 = *(const float4*)(el + (size_t)sv * 4);
      t0 += __expf(leaky(e4.x + erv.x)); t1 += __expf(leaky(e4.y + erv.y));
      t2 += __expf(leaky(e4.z + erv.z)); t3 += __expf(leaky(e4.w + erv.w));
    }
#pragma unroll
    for (int off = 8; off; off >>= 1) {
      t0 += __shfl_xor(t0, off); t1 += __shfl_xor(t1, off);
      t2 += __shfl_xor(t2, off); t3 += __shfl_xor(t3, off);
    }
    float si0 = t0 > 0.f ? 1.f / t0 : 0.f;
    float si1 = t1 > 0.f ? 1.f / t1 : 0.f;
    float si2 = t2 > 0.f ? 1.f / t2 : 0.f;
    float si3 = t3 > 0.f ? 1.f / t3 : 0.f;
    // pass B: each lane owns channels ci*8..ci*8+8 of the xh row
    float A[4][8] = {};
    for (int k = 0; k < len; ++k) {
      float ah0, ah1, ah2, ah3;
      int sidx;
      if (k < 64) {
        int jj = k >> 4, sl = (g << 4) | (k & 15);
        if (jj == 0) {
          ah0 = __shfl(a0[0], sl); ah1 = __shfl(a1[0], sl);
          ah2 = __shfl(a2[0], sl); ah3 = __shfl(a3[0], sl); sidx = __shfl(sr[0], sl);
        } else if (jj == 1) {
          ah0 = __shfl(a0[1], sl); ah1 = __shfl(a1[1], sl);
          ah2 = __shfl(a2[1], sl); ah3 = __shfl(a3[1], sl); sidx = __shfl(sr[1], sl);
        } else if (jj == 2) {
          ah0 = __shfl(a0[2], sl); ah1 = __shfl(a1[2], sl);
          ah2 = __shfl(a2[2], sl); ah3 = __shfl(a3[2], sl); sidx = __shfl(sr[2], sl);
        } else {
          ah0 = __shfl(a0[3], sl); ah1 = __shfl(a1[3], sl);
          ah2 = __shfl(a2[3], sl); ah3 = __shfl(a3[3], sl); sidx = __shfl(sr[3], sl);
        }
      } else {
        sidx = src[s0 + k];
        float4 e4 = *(const float4*)(el + (size_t)sidx * 4);
        ah0 = __expf(leaky(e4.x + erv.x)); ah1 = __expf(leaky(e4.y + erv.y));
        ah2 = __expf(leaky(e4.z + erv.z)); ah3 = __expf(leaky(e4.w + erv.w));
      }
      half8 xv = *(const half8*)(xh + (size_t)sidx * 128 + ci * 8);
#pragma unroll
      for (int c = 0; c < 8; ++c) {
        float xc = (float)xv[c];
        A[0][c] += ah0 * xc; A[1][c] += ah1 * xc;
        A[2][c] += ah2 * xc; A[3][c] += ah3 * xc;
      }
    }
    float si[4] = {si0, si1, si2, si3};
#pragma unroll
    for (int h = 0; h < 4; ++h) {
      half8 o;
#pragma unroll
      for (int c = 0; c < 8; ++c) o[c] = (_Float16)(A[h][c] * si[h]);
      *(half8*)(&As[(h * 64 + j) * 128 + ((ci ^ (j & 7)) << 3)]) = o;
    }
  }
  __syncthreads();

  // GEMM: head h = wid>>1 (0..3), row-half wi = wid&1 (rows wi*32..wi*32+32)
  const int h = wid >> 1, wi = wid & 1;
  const int cl = ci, quad = g;
  const bool need_er = (m0 < N_DST1);
  f32x4 acc[2][4] = {};
  for (int ks = 0; ks < 4; ++ks) {
    int kc = ks * 4 + quad;
    half8 af[2], bf[4];
    for (int i = 0; i < 2; ++i) {
      int ra = wi * 32 + 16 * i + cl;
      af[i] = *(const half8*)(&As[(h * 64 + ra) * 128 + ((kc ^ (ra & 7)) << 3)]);
    }
    for (int j2 = 0; j2 < 4; ++j2) {
      int rb = 16 * j2 + cl;
      bf[j2] = *(const half8*)(BT + (size_t)(h * 64 + rb) * 128 + kc * 8);
    }
    for (int i = 0; i < 2; ++i)
      for (int j2 = 0; j2 < 4; ++j2)
        acc[i][j2] = __builtin_amdgcn_mfma_f32_16x16x32_f16(af[i], bf[j2], acc[i][j2], 0, 0, 0);
  }
  f32x4 el1p[2][4] = {}, er1p[2][4] = {};
  for (int j2 = 0; j2 < 4; ++j2) {
    int gcol = h * 64 + 16 * j2 + cl;
    float bias = b[gcol];
    f32x4 wlv = *(const f32x4*)(wl1 + (size_t)gcol * 4);
    f32x4 wrv = *(const f32x4*)(wr1 + (size_t)gcol * 4);
    for (int i = 0; i < 2; ++i) {
      int r0 = m0 + wi * 32 + 16 * i + quad * 4;
      for (int r = 0; r < 4; ++r) {
        float v = fmaxf(acc[i][j2][r] + bias, 0.f);
        h0[(size_t)(r0 + r) * 256 + gcol] = (_Float16)v;
        el1p[i][r] += wlv * v;
        if (need_er) er1p[i][r] += wrv * v;
      }
    }
  }
#pragma unroll
  for (int off = 1; off < 16; off <<= 1)
#pragma unroll
    for (int i = 0; i < 2; ++i)
#pragma unroll
      for (int r = 0; r < 4; ++r)
#pragma unroll
        for (int c = 0; c < 4; ++c) {
          el1p[i][r][c] += __shfl_xor(el1p[i][r][c], off);
          if (need_er) er1p[i][r][c] += __shfl_xor(er1p[i][r][c], off);
        }
  if (cl == 0) {
    for (int i = 0; i < 2; ++i)
      for (int r = 0; r < 4; ++r) {
        int rl = wi * 32 + 16 * i + quad * 4 + r;
#pragma unroll
        for (int hh = 0; hh < 4; ++hh) {
          atomicAdd(&elds[rl][hh], el1p[i][r][hh]);
          if (need_er) atomicAdd(&elds[rl][4 + hh], er1p[i][r][hh]);
        }
      }
  }
  __syncthreads();
  if (t < 128) {
    int r = t >> 1, half = t & 1, row = m0 + r;
    if (half == 0) *(float4*)(el1 + (size_t)row * 4) = *(float4*)&elds[r][0];
    else if (row < N_DST1) *(float4*)(er1 + (size_t)row * 4) = *(float4*)&elds[r][4];
  }
}

// layer-1 aggregation: wave-per-node, inline score, 8 ch/lane over 256 cols
__global__ __launch_bounds__(256) void agg1s_kernel(
    const int* __restrict__ src, const int* __restrict__ seg,
    const float* __restrict__ el, const float* __restrict__ er,
    const _Float16* __restrict__ h0, _Float16* __restrict__ axh1) {
  const int lane = threadIdx.x & 63, w = threadIdx.x >> 6;
  const int n = blockIdx.x * 4 + w;
  int s0 = seg[n], len = seg[n + 1] - s0;
  float4 erv = *(const float4*)(er + (size_t)n * 4);
  float a0 = 0.f, a1 = 0.f, a2 = 0.f, a3 = 0.f;
  float t0 = 0.f, t1 = 0.f, t2 = 0.f, t3 = 0.f;
  int sreg = 0;
  if (lane < len) {
    sreg = src[s0 + lane];
    float4 e4 = *(const float4*)(el + (size_t)sreg * 4);
    a0 = __expf(leaky(e4.x + erv.x)); a1 = __expf(leaky(e4.y + erv.y));
    a2 = __expf(leaky(e4.z + erv.z)); a3 = __expf(leaky(e4.w + erv.w));
    t0 = a0; t1 = a1; t2 = a2; t3 = a3;
  }
  for (int idx = 64 + lane; idx < len; idx += 64) {
    int s = src[s0 + idx];
    float4 e4 = *(const float4*)(el + (size_t)s * 4);
    t0 += __expf(leaky(e4.x + erv.x)); t1 += __expf(leaky(e4.y + erv.y));
    t2 += __expf(leaky(e4.z + erv.z)); t3 += __expf(leaky(e4.w + erv.w));
  }
#pragma unroll
  for (int off = 32; off; off >>= 1) {
    t0 += __shfl_xor(t0, off); t1 += __shfl_xor(t1, off);
    t2 += __shfl_xor(t2, off); t3 += __shfl_xor(t3, off);
  }
  float si0 = t0 > 0.f ? 1.f / t0 : 0.f;
  float si1 = t1 > 0.f ? 1.f / t1 : 0.f;
  float si2 = t2 > 0.f ? 1.f / t2 : 0.f;
  float si3 = t3 > 0.f ? 1.f / t3 : 0.f;
  const int g = lane >> 5, ci = lane & 31;
  float A[4][8] = {};
  int iters = (len + 1) >> 1;
  for (int k = 0; k < iters; ++k) {
    int idx = g + 2 * k;
    int sl = idx < 64 ? idx : 0;
    float ah0 = __shfl(a0, sl), ah1 = __shfl(a1, sl);
    float ah2 = __shfl(a2, sl), ah3 = __shfl(a3, sl);
    int sidx = __shfl(sreg, sl);
    if (idx >= 64 && idx < len) {
      sidx = src[s0 + idx];
      float4 e4 = *(const float4*)(el + (size_t)sidx * 4);
      ah0 = __expf(leaky(e4.x + erv.x)); ah1 = __expf(leaky(e4.y + erv.y));
      ah2 = __expf(leaky(e4.z + erv.z)); ah3 = __expf(leaky(e4.w + erv.w));
    }
    if (idx < len) {
      half8 xv = *(const half8*)(h0 + (size_t)sidx * 256 + ci * 8);
#pragma unroll
      for (int c = 0; c < 8; ++c) {
        float xc = (float)xv[c];
        A[0][c] += ah0 * xc; A[1][c] += ah1 * xc;
        A[2][c] += ah2 * xc; A[3][c] += ah3 * xc;
      }
    }
  }
#pragma unroll
  for (int h = 0; h < 4; ++h)
#pragma unroll
    for (int c = 0; c < 8; ++c) A[h][c] += __shfl_xor(A[h][c], 32);
  if (g == 0) {
    float si[4] = {si0, si1, si2, si3};
#pragma unroll
    for (int h = 0; h < 4; ++h) {
      half8 o;
#pragma unroll
      for (int c = 0; c < 8; ++c) o[c] = (_Float16)(A[h][c] * si[h]);
      *(half8*)(axh1 + ((size_t)n * 4 + h) * 256 + ci * 8) = o;
    }
  }
}

// out[m, 0:47] = log_softmax( axh1[m,:,:] (1024) @ BTs (1024 x 64, pre-scaled 0.25) + bmean )
__global__ __launch_bounds__(256) void gemm_out_kernel(
    const _Float16* __restrict__ axh1, const _Float16* __restrict__ BTs,
    const float* __restrict__ b1, float* __restrict__ out) {
  __shared__ _Float16 As[64 * 128];
  __shared__ _Float16 Bs[64 * 128];
  const int t = threadIdx.x, lane = t & 63, wid = t >> 6;
  const int m0 = blockIdx.x * 64;
  f32x4 acc[4] = {};
  for (int k0 = 0; k0 < 1024; k0 += 128) {
    for (int i = 0; i < 4; ++i) {
      int c = t + 256 * i, row = c >> 4, j = c & 15;
      int sw = ((j ^ (row & 7)) << 3);
      *(half8*)(&As[row * 128 + sw]) =
          *(const half8*)(axh1 + (size_t)(m0 + row) * 1024 + k0 + j * 8);
      *(half8*)(&Bs[row * 128 + sw]) =
          *(const half8*)(BTs + (size_t)row * 1024 + k0 + j * 8);
    }
    __syncthreads();
    const int wm = wid * 16;
    for (int ks = 0; ks < 4; ++ks) {
      int kc = ks * 4 + (lane >> 4);
      int ra = wm + (lane & 15);
      half8 af = *(const half8*)(&As[ra * 128 + ((kc ^ (ra & 7)) << 3)]);
      for (int j2 = 0; j2 < 4; ++j2) {
        int rb = 16 * j2 + (lane & 15);
        half8 bf = *(const half8*)(&Bs[rb * 128 + ((kc ^ (rb & 7)) << 3)]);
        acc[j2] = __builtin_amdgcn_mfma_f32_16x16x32_f16(af, bf, acc[j2], 0, 0, 0);
      }
    }
    __syncthreads();
  }
  int quad = lane >> 4, cl = lane & 15;
  float bm[3];
  for (int j2 = 0; j2 < 3; ++j2) {
    int col = 16 * j2 + cl;
    bm[j2] = (col < 47) ? 0.25f * (b1[col] + b1[col + 47] + b1[col + 94] + b1[col + 141]) : 0.f;
  }
  for (int r = 0; r < 4; ++r) {
    int row = m0 + wid * 16 + quad * 4 + r;
    float v[3];
    float mx = -1e30f;
    for (int j2 = 0; j2 < 3; ++j2) {
      int col = 16 * j2 + cl;
      v[j2] = acc[j2][r] + bm[j2];
      if (col < 47) mx = fmaxf(mx, v[j2]);
    }
    for (int off = 8; off; off >>= 1) mx = fmaxf(mx, __shfl_xor(mx, off));
    float s = 0.f;
    for (int j2 = 0; j2 < 3; ++j2) {
      int col = 16 * j2 + cl;
      if (col < 47) s += __expf(v[j2] - mx);
    }
    for (int off = 8; off; off >>= 1) s += __shfl_xor(s, off);
    float lse = mx + __logf(s);
    for (int j2 = 0; j2 < 3; ++j2) {
      int col = 16 * j2 + cl;
      if (col < 47) out[(size_t)row * 47 + col] = v[j2] - lse;
    }
  }
}

extern "C" void kernel_launch(void* const* d_in, const int* in_sizes, int n_in,
                              void* d_out, int out_size, void* d_ws, size_t ws_size,
                              hipStream_t stream) {
  const float* x   = (const float*)d_in[0];
  const int* src0  = (const int*)d_in[1];
  const int* dst0  = (const int*)d_in[2];
  const int* src1  = (const int*)d_in[3];
  const int* dst1  = (const int*)d_in[4];
  const float* Ws0 = (const float*)d_in[5];
  const float* Wd0 = (const float*)d_in[6];
  const float* al0 = (const float*)d_in[7];
  const float* ar0 = (const float*)d_in[8];
  const float* b0  = (const float*)d_in[9];
  const float* Ws1 = (const float*)d_in[10];
  const float* Wd1 = (const float*)d_in[11];
  const float* al1 = (const float*)d_in[12];
  const float* ar1 = (const float*)d_in[13];
  const float* b1  = (const float*)d_in[14];

  char* w = (char*)d_ws;
  auto alloc = [&](size_t bytes) {
    char* p = w;
    w += (bytes + 255) & ~(size_t)255;
    return p;
  };
  _Float16* xh   = (_Float16*)alloc((size_t)N_SRC0 * 128 * 2);   // 128 MB
  _Float16* h0   = (_Float16*)alloc((size_t)N_DST0 * 256 * 2);   // 33.5 MB
  _Float16* axh1 = (_Float16*)alloc((size_t)N_DST1 * 1024 * 2);  // 16.8 MB
  float* el0     = (float*)alloc((size_t)N_SRC0 * 4 * 4);
  float* er0     = (float*)alloc((size_t)N_DST0 * 4 * 4);
  float* el1     = (float*)alloc((size_t)N_DST0 * 4 * 4);
  float* er1     = (float*)alloc((size_t)N_DST1 * 4 * 4);
  int* seg0      = (int*)alloc((size_t)(N_DST0 + 1) * 4);
  int* seg1      = (int*)alloc((size_t)(N_DST1 + 1) * 4);
  _Float16* BT0  = (_Float16*)alloc(256 * 128 * 2);
  _Float16* BTs  = (_Float16*)alloc(64 * 1024 * 2);
  _Float16* WLR0 = (_Float16*)alloc(16 * 128 * 2);
  float* wl1     = (float*)alloc(256 * 4 * 4);
  float* wr1     = (float*)alloc(256 * 4 * 4);

  prep_kernel<<<(PREP_TOTAL + 255) / 256, 256, 0, stream>>>(
      Ws0, Wd0, al0, ar0, Ws1, Wd1, al1, ar1, dst0, dst1,
      BTs, BT0, WLR0, wl1, wr1, seg0, seg1);
  cvt_elr_mfma_kernel<<<(N_SRC0 + 127) / 128, 256, 0, stream>>>(x, WLR0, xh, el0, er0,
                                                                N_SRC0, N_DST0);
  agg_gemm0_kernel<<<N_DST0 / 64, 512, 0, stream>>>(src0, seg0, el0, er0, xh, BT0, b0,
                                                    wl1, wr1, h0, el1, er1);
  agg1s_kernel<<<N_DST1 / 4, 256, 0, stream>>>(src1, seg1, el1, er1, h0, axh1);
  gemm_out_kernel<<<N_DST1 / 64, 256, 0, stream>>>(axh1, BTs, b1, (float*)d_out);
}